// Round 7
// baseline (58.895 us; speedup 1.0000x reference)
//
#include <hip/hip_runtime.h>
#include <hip/hip_bf16.h>
#include <utility>

#define LOG2E 1.4426950408889634f

#if __has_builtin(__builtin_amdgcn_exp2f)
#define EXP2F(x) __builtin_amdgcn_exp2f(x)
#else
#define EXP2F(x) exp2f(x)
#endif

// ---------------------------------------------------------------------------
// Kernel 1: ONE wave (64 threads). Register-resident Cholesky.
// Lane l owns row l of Kzz in r[0..63].
//
// R7 fix: R6 still showed FETCH_SIZE ~61 KB + VGPR_Count 84 -> the triangular
// inner loop (trip count depends on k) defeated full unroll, so r[] was
// runtime-indexed and lived in SCRATCH, not registers (rule #20). Each step
// is now a chol_step<K> template instantiated over integer_sequence<0..63>:
// K is a compile-time constant, inner bounds K+1..64 are constant, pragma
// unroll fully expands, every r[] index is compile-time. rd[] is dropped;
// the solve re-reads the diagonal from the LDS copy of L (uniform broadcast
// reads, conflict-free) to cut register demand.
//
// ws layout (per m, 8 floats):
//   [0..2] = Z[m]/ell, [3] = -0.5*log2e*||Z[m]/ell||^2,
//   [4] = sf^2*W[m][0], [5] = sf^2*W[m][1], [6..7] = pad
// ---------------------------------------------------------------------------

template<int K>
__device__ __forceinline__ void chol_step(float (&r)[64]) {
    float dk  = __shfl(r[K], K);        // A[k][k] after prior updates
    float inv = 1.0f / sqrtf(dk);
    float lk  = r[K] * inv;             // lane l: L[l][K] (valid l >= K)
    r[K] = lk;                          // lane K holds L[K][K] = sqrt(dk)
#pragma unroll
    for (int j = K + 1; j < 64; ++j) {  // constant trip count: full unroll
        float ljk = __shfl(lk, j);      // L[j][K], compile-time source lane
        r[j] = fmaf(-lk, ljk, r[j]);    // A[l][j] -= L[l][K]*L[j][K]
    }
}

template<int... Ks>
__device__ __forceinline__ void chol_run(float (&r)[64],
                                         std::integer_sequence<int, Ks...>) {
    (chol_step<Ks>(r), ...);
}

__global__ __launch_bounds__(64, 1)
void gp_precompute(const float* __restrict__ Z, const float* __restrict__ U,
                   const float* __restrict__ sf_p, const float* __restrict__ ell_p,
                   float* __restrict__ ws) {
    __shared__ float Lsh[64 * 65];
    const int lane = threadIdx.x;          // 64 threads = 1 wave
    const float sf  = sf_p[0];
    const float ell = ell_p[0];
    const float inv_ell = 1.0f / ell;
    const float sf2 = sf * sf;

    const float z0 = Z[lane * 3 + 0] * inv_ell;
    const float z1 = Z[lane * 3 + 1] * inv_ell;
    const float z2 = Z[lane * 3 + 2] * inv_ell;

    // Row `lane` of Kzz, entirely in registers (constant trip count).
    float r[64];
#pragma unroll
    for (int j = 0; j < 64; ++j) {
        float dx = z0 - __shfl(z0, j);
        float dy = z1 - __shfl(z1, j);
        float dz = z2 - __shfl(z2, j);
        float sq = dx * dx + dy * dy + dz * dz;
        r[j] = sf2 * EXP2F(-0.5f * LOG2E * sq);
    }

    // Right-looking Cholesky, template-forced full unroll.
    chol_run(r, std::make_integer_sequence<int, 64>{});

    // Spill L to LDS: row l at stride 65 -> writes and row-reads conflict-free.
#pragma unroll
    for (int j = 0; j < 64; ++j) Lsh[lane * 65 + j] = r[j];
    __syncthreads();

    // Solve L^T W = U (column sweep): s_l = U[l][o] - sum_{i>l} L[i][l] W[i].
    // Diagonal reciprocals come from uniform (broadcast) LDS reads; the
    // divisions are independent of the serial s-chain and hoist freely.
    float s0 = U[lane * 2 + 0];
    float s1 = U[lane * 2 + 1];
    float w0v = 0.0f, w1v = 0.0f;
#pragma unroll
    for (int i = 63; i >= 0; --i) {
        float rdi = 1.0f / Lsh[i * 65 + i];   // 1/L[i][i], uniform
        float w0 = __shfl(s0, i) * rdi;       // W[i][0]
        float w1 = __shfl(s1, i) * rdi;       // W[i][1]
        float a  = Lsh[i * 65 + lane];        // L[i][lane] (valid lane <= i)
        s0 = fmaf(-a, w0, s0);                // garbage on lanes >= i is never
        s1 = fmaf(-a, w1, s1);                //   read after extraction
        if (lane == i) { w0v = w0; w1v = w1; }
    }

    const float dm = -0.5f * LOG2E * (z0 * z0 + z1 * z1 + z2 * z2);
    ws[lane * 8 + 0] = z0;
    ws[lane * 8 + 1] = z1;
    ws[lane * 8 + 2] = z2;
    ws[lane * 8 + 3] = dm;
    ws[lane * 8 + 4] = sf2 * w0v;
    ws[lane * 8 + 5] = sf2 * w1v;
    ws[lane * 8 + 6] = 0.0f;
    ws[lane * 8 + 7] = 0.0f;
}

// ---------------------------------------------------------------------------
// Kernel 2 (byte-identical to R1/R2/R6): out[i,:] = sum_m exp2(c_i+d_m+xt.z)*W[m,:]
// ---------------------------------------------------------------------------
__global__ __launch_bounds__(256) void gp_forward(const float* __restrict__ X,
                                                  const float* __restrict__ ws,
                                                  const float* __restrict__ ell_p,
                                                  float* __restrict__ out, int n) {
    __shared__ float4 P[128];   // 64 structs of {zs0,zs1,zs2,dm | w0,w1,0,0}
    for (int i = threadIdx.x; i < 128; i += 256)
        P[i] = ((const float4*)ws)[i];
    const float inv_ell = 1.0f / ell_p[0];
    __syncthreads();

    const int base = blockIdx.x * (256 * 4) + threadIdx.x;

    float xt0[4], xt1[4], xt2[4], c[4];
#pragma unroll
    for (int p = 0; p < 4; ++p) {
        int i = base + p * 256;
        int ii = (i < n) ? i : 0;            // clamp; result masked on store
        float xs0 = X[ii * 3 + 0] * inv_ell;
        float xs1 = X[ii * 3 + 1] * inv_ell;
        float xs2 = X[ii * 3 + 2] * inv_ell;
        c[p]  = -0.5f * LOG2E * (xs0 * xs0 + xs1 * xs1 + xs2 * xs2);
        xt0[p] = xs0 * LOG2E;
        xt1[p] = xs1 * LOG2E;
        xt2[p] = xs2 * LOG2E;
    }

    float acc0[4] = {0.f, 0.f, 0.f, 0.f};
    float acc1[4] = {0.f, 0.f, 0.f, 0.f};

#pragma unroll 4
    for (int m = 0; m < 64; ++m) {
        const float4 a = P[2 * m + 0];   // zs0, zs1, zs2, dm
        const float4 b = P[2 * m + 1];   // w0, w1, pad, pad
#pragma unroll
        for (int p = 0; p < 4; ++p) {
            float arg = fmaf(xt0[p], a.x,
                        fmaf(xt1[p], a.y,
                        fmaf(xt2[p], a.z, c[p] + a.w)));
            float e = EXP2F(arg);
            acc0[p] = fmaf(e, b.x, acc0[p]);
            acc1[p] = fmaf(e, b.y, acc1[p]);
        }
    }

    float2* out2 = (float2*)out;
#pragma unroll
    for (int p = 0; p < 4; ++p) {
        int i = base + p * 256;
        if (i < n) out2[i] = make_float2(acc0[p], acc1[p]);
    }
}

extern "C" void kernel_launch(void* const* d_in, const int* in_sizes, int n_in,
                              void* d_out, int out_size, void* d_ws, size_t ws_size,
                              hipStream_t stream) {
    // setup_inputs order: t, X, Z, U, sf, ell
    const float* X    = (const float*)d_in[1];
    const float* Z    = (const float*)d_in[2];
    const float* U    = (const float*)d_in[3];
    const float* sf   = (const float*)d_in[4];
    const float* ell  = (const float*)d_in[5];
    float* out = (float*)d_out;
    float* ws  = (float*)d_ws;
    const int N = in_sizes[1] / 3;

    gp_precompute<<<1, 64, 0, stream>>>(Z, U, sf, ell, ws);

    const int PTS_PER_BLOCK = 256 * 4;
    const int blocks = (N + PTS_PER_BLOCK - 1) / PTS_PER_BLOCK;
    gp_forward<<<blocks, 256, 0, stream>>>(X, ws, ell, out, N);
}

// Round 8
// 44.346 us; speedup vs baseline: 1.3281x; 1.3281x over previous
//
#include <hip/hip_runtime.h>
#include <hip/hip_bf16.h>
#include <utility>

#define LOG2E 1.4426950408889634f

#if __has_builtin(__builtin_amdgcn_exp2f)
#define EXP2F(x) __builtin_amdgcn_exp2f(x)
#else
#define EXP2F(x) exp2f(x)
#endif

// Uniform broadcast from a compile-time lane: VALU v_readlane, no LDS pipe.
#define RDLANE(x, l) __int_as_float(__builtin_amdgcn_readlane(__float_as_int(x), (l)))

// ---------------------------------------------------------------------------
// R8: no arrays at all. R7 showed that even fully constant-indexed float r[64]
// stays in scratch (FETCH 66KB, VGPR 68) -- promote-alloca gives up. Row state
// is now 4x ext_vector_type(16) (SSA vectors, the MFMA-accumulator pattern),
// accessed only via get<J>/set<J> with if-constexpr -> insert/extractelement.
// Column broadcasts via v_readlane (literal lane). Diagonal slots hold
// 1/L[k][k] so the solve needs no divides.
// ---------------------------------------------------------------------------
typedef float f16v __attribute__((ext_vector_type(16)));
struct Rows { f16v v0, v1, v2, v3; };

template<int J> __device__ __forceinline__ float getR(const Rows& r) {
    if constexpr (J < 16)      return r.v0[J];
    else if constexpr (J < 32) return r.v1[J - 16];
    else if constexpr (J < 48) return r.v2[J - 32];
    else                       return r.v3[J - 48];
}
template<int J> __device__ __forceinline__ void setR(Rows& r, float x) {
    if constexpr (J < 16)      r.v0[J] = x;
    else if constexpr (J < 32) r.v1[J - 16] = x;
    else if constexpr (J < 48) r.v2[J - 32] = x;
    else                       r.v3[J - 48] = x;
}

// --- Kzz row init: r[J] = sf2 * exp2(-0.5*log2e*||z_l - z_J||^2) ----------
template<int J>
__device__ __forceinline__ void init_pt(Rows& r, float z0, float z1, float z2, float sf2) {
    float dx = z0 - RDLANE(z0, J);
    float dy = z1 - RDLANE(z1, J);
    float dz = z2 - RDLANE(z2, J);
    float sq = dx * dx + dy * dy + dz * dz;
    setR<J>(r, sf2 * EXP2F(-0.5f * LOG2E * sq));
}
template<int... Js>
__device__ __forceinline__ void init_all(Rows& r, float z0, float z1, float z2, float sf2,
                                         std::integer_sequence<int, Js...>) {
    (init_pt<Js>(r, z0, z1, z2, sf2), ...);
}

// --- Cholesky: rank-1 update column J at step K ---------------------------
template<int K, int J>
__device__ __forceinline__ void chol_upd(Rows& r, float lk) {
    float ljk = RDLANE(lk, J);                 // L[J][K]
    setR<J>(r, fmaf(-lk, ljk, getR<J>(r)));    // A[l][J] -= L[l][K]*L[J][K]
}
template<int K, int... Js>
__device__ __forceinline__ void chol_inner(Rows& r, float lk,
                                           std::integer_sequence<int, Js...>) {
    (chol_upd<K, K + 1 + Js>(r, lk), ...);
}
template<int K>
__device__ __forceinline__ void chol_step(Rows& r, int lane) {
    float rk  = getR<K>(r);
    float dk  = RDLANE(rk, K);                 // A[K][K] (uniform)
    float inv = 1.0f / sqrtf(dk);              // 1/L[K][K] (uniform)
    float lk  = rk * inv;                      // L[l][K] for l >= K
    setR<K>(r, (lane == K) ? inv : lk);        // diag slot holds 1/L[K][K]
    chol_inner<K>(r, lk, std::make_integer_sequence<int, 63 - K>{});
}
template<int... Ks>
__device__ __forceinline__ void chol_all(Rows& r, int lane,
                                         std::integer_sequence<int, Ks...>) {
    (chol_step<Ks>(r, lane), ...);
}

// --- LDS spill / transposed reload (stride 65: conflict-free both ways) ---
template<int... Js>
__device__ __forceinline__ void spill_all(const Rows& r, float* Lsh, int lane,
                                          std::integer_sequence<int, Js...>) {
    ((Lsh[lane * 65 + Js] = getR<Js>(r)), ...);
}
template<int... Is>
__device__ __forceinline__ void load_t_all(Rows& lt, const float* Lsh, int lane,
                                           std::integer_sequence<int, Is...>) {
    (setR<Is>(lt, Lsh[Is * 65 + lane]), ...);
}

// --- Back-substitution L^T W = U, descending i, pure VALU -----------------
template<int I>
__device__ __forceinline__ void solve_step(const Rows& lt, int lane,
                                           float& s0, float& s1,
                                           float& w0v, float& w1v) {
    float a   = getR<I>(lt);                   // L[I][lane]; lane I: 1/L[I][I]
    float rdi = RDLANE(a, I);                  // 1/L[I][I]
    float w0  = RDLANE(s0, I) * rdi;           // W[I][0]
    float w1  = RDLANE(s1, I) * rdi;           // W[I][1]
    s0 = fmaf(-a, w0, s0);                     // lanes >= I polluted after use
    s1 = fmaf(-a, w1, s1);
    w0v = (lane == I) ? w0 : w0v;
    w1v = (lane == I) ? w1 : w1v;
}
template<int... Is>
__device__ __forceinline__ void solve_all(const Rows& lt, int lane,
                                          float& s0, float& s1,
                                          float& w0v, float& w1v,
                                          std::integer_sequence<int, Is...>) {
    (solve_step<63 - Is>(lt, lane, s0, s1, w0v, w1v), ...);
}

__global__ __launch_bounds__(64, 1)
void gp_precompute(const float* __restrict__ Z, const float* __restrict__ U,
                   const float* __restrict__ sf_p, const float* __restrict__ ell_p,
                   float* __restrict__ ws) {
    __shared__ float Lsh[64 * 65];
    const int lane = threadIdx.x;          // 64 threads = 1 wave
    const float sf  = sf_p[0];
    const float ell = ell_p[0];
    const float inv_ell = 1.0f / ell;
    const float sf2 = sf * sf;

    const float z0 = Z[lane * 3 + 0] * inv_ell;
    const float z1 = Z[lane * 3 + 1] * inv_ell;
    const float z2 = Z[lane * 3 + 2] * inv_ell;

    Rows rows;
    init_all(rows, z0, z1, z2, sf2, std::make_integer_sequence<int, 64>{});
    chol_all(rows, lane, std::make_integer_sequence<int, 64>{});

    spill_all(rows, Lsh, lane, std::make_integer_sequence<int, 64>{});
    __syncthreads();

    Rows lt;
    load_t_all(lt, Lsh, lane, std::make_integer_sequence<int, 64>{});

    float s0 = U[lane * 2 + 0];
    float s1 = U[lane * 2 + 1];
    float w0v = 0.0f, w1v = 0.0f;
    solve_all(lt, lane, s0, s1, w0v, w1v, std::make_integer_sequence<int, 64>{});

    const float dm = -0.5f * LOG2E * (z0 * z0 + z1 * z1 + z2 * z2);
    ws[lane * 8 + 0] = z0;
    ws[lane * 8 + 1] = z1;
    ws[lane * 8 + 2] = z2;
    ws[lane * 8 + 3] = dm;
    ws[lane * 8 + 4] = sf2 * w0v;
    ws[lane * 8 + 5] = sf2 * w1v;
    ws[lane * 8 + 6] = 0.0f;
    ws[lane * 8 + 7] = 0.0f;
}

// ---------------------------------------------------------------------------
// Kernel 2 (byte-identical to R1/R2/R6/R7): out[i,:] = sum_m exp2(c_i+d_m+xt.z)*W[m,:]
// ---------------------------------------------------------------------------
__global__ __launch_bounds__(256) void gp_forward(const float* __restrict__ X,
                                                  const float* __restrict__ ws,
                                                  const float* __restrict__ ell_p,
                                                  float* __restrict__ out, int n) {
    __shared__ float4 P[128];   // 64 structs of {zs0,zs1,zs2,dm | w0,w1,0,0}
    for (int i = threadIdx.x; i < 128; i += 256)
        P[i] = ((const float4*)ws)[i];
    const float inv_ell = 1.0f / ell_p[0];
    __syncthreads();

    const int base = blockIdx.x * (256 * 4) + threadIdx.x;

    float xt0[4], xt1[4], xt2[4], c[4];
#pragma unroll
    for (int p = 0; p < 4; ++p) {
        int i = base + p * 256;
        int ii = (i < n) ? i : 0;            // clamp; result masked on store
        float xs0 = X[ii * 3 + 0] * inv_ell;
        float xs1 = X[ii * 3 + 1] * inv_ell;
        float xs2 = X[ii * 3 + 2] * inv_ell;
        c[p]  = -0.5f * LOG2E * (xs0 * xs0 + xs1 * xs1 + xs2 * xs2);
        xt0[p] = xs0 * LOG2E;
        xt1[p] = xs1 * LOG2E;
        xt2[p] = xs2 * LOG2E;
    }

    float acc0[4] = {0.f, 0.f, 0.f, 0.f};
    float acc1[4] = {0.f, 0.f, 0.f, 0.f};

#pragma unroll 4
    for (int m = 0; m < 64; ++m) {
        const float4 a = P[2 * m + 0];   // zs0, zs1, zs2, dm
        const float4 b = P[2 * m + 1];   // w0, w1, pad, pad
#pragma unroll
        for (int p = 0; p < 4; ++p) {
            float arg = fmaf(xt0[p], a.x,
                        fmaf(xt1[p], a.y,
                        fmaf(xt2[p], a.z, c[p] + a.w)));
            float e = EXP2F(arg);
            acc0[p] = fmaf(e, b.x, acc0[p]);
            acc1[p] = fmaf(e, b.y, acc1[p]);
        }
    }

    float2* out2 = (float2*)out;
#pragma unroll
    for (int p = 0; p < 4; ++p) {
        int i = base + p * 256;
        if (i < n) out2[i] = make_float2(acc0[p], acc1[p]);
    }
}

extern "C" void kernel_launch(void* const* d_in, const int* in_sizes, int n_in,
                              void* d_out, int out_size, void* d_ws, size_t ws_size,
                              hipStream_t stream) {
    // setup_inputs order: t, X, Z, U, sf, ell
    const float* X    = (const float*)d_in[1];
    const float* Z    = (const float*)d_in[2];
    const float* U    = (const float*)d_in[3];
    const float* sf   = (const float*)d_in[4];
    const float* ell  = (const float*)d_in[5];
    float* out = (float*)d_out;
    float* ws  = (float*)d_ws;
    const int N = in_sizes[1] / 3;

    gp_precompute<<<1, 64, 0, stream>>>(Z, U, sf, ell, ws);

    const int PTS_PER_BLOCK = 256 * 4;
    const int blocks = (N + PTS_PER_BLOCK - 1) / PTS_PER_BLOCK;
    gp_forward<<<blocks, 256, 0, stream>>>(X, ws, ell, out, N);
}

// Round 9
// 42.611 us; speedup vs baseline: 1.3821x; 1.0407x over previous
//
#include <hip/hip_runtime.h>
#include <hip/hip_bf16.h>
#include <utility>

#define LOG2E 1.4426950408889634f

#if __has_builtin(__builtin_amdgcn_exp2f)
#define EXP2F(x) __builtin_amdgcn_exp2f(x)
#else
#define EXP2F(x) exp2f(x)
#endif

#if __has_builtin(__builtin_amdgcn_rsqf)
#define RSQ(x) __builtin_amdgcn_rsqf(x)
#else
#define RSQ(x) (1.0f / sqrtf(x))
#endif

// readlane: lane may be a literal OR a runtime-uniform (SGPR) value.
#define RDLANE(x, l) __int_as_float(__builtin_amdgcn_readlane(__float_as_int(x), (l)))

// ---------------------------------------------------------------------------
// R9: code-size attack. R8 evidence: FETCH_SIZE ~64KB == straight-line code
// size (4K-inst unrolled Cholesky), VALUBusy ~2.6% on the active CU -> the
// single wave stalls on cold icache (serialized L2 misses), not on data.
// New structure: ROLLED outer k-loop (hot icache) + template-unrolled padded
// inner update (compile-time register indices). The only runtime register
// read, r[k], is a 63-cndmask select tree (uniform k, 6 CSE'd bit tests).
// Finalized columns are sunk to LDS at their own step, so padded updates to
// dead columns are harmless garbage. Three phases shrink pad width 64/32/16.
// ---------------------------------------------------------------------------
typedef float f16v __attribute__((ext_vector_type(16)));
struct Rows { f16v v0, v1, v2, v3; };

template<int J> __device__ __forceinline__ float getR(const Rows& r) {
    if constexpr (J < 16)      return r.v0[J];
    else if constexpr (J < 32) return r.v1[J - 16];
    else if constexpr (J < 48) return r.v2[J - 32];
    else                       return r.v3[J - 48];
}
template<int J> __device__ __forceinline__ void setR(Rows& r, float x) {
    if constexpr (J < 16)      r.v0[J] = x;
    else if constexpr (J < 32) r.v1[J - 16] = x;
    else if constexpr (J < 48) r.v2[J - 32] = x;
    else                       r.v3[J - 48] = x;
}

// Select r[k] for runtime (uniform) k from regs [LO, LO+W). W pow2, LO%W==0.
template<int LO, int W>
__device__ __forceinline__ float selR(const Rows& r, int k) {
    if constexpr (W == 1) {
        return getR<LO>(r);
    } else {
        float lo = selR<LO, W / 2>(r, k);
        float hi = selR<LO + W / 2, W / 2>(r, k);
        return (k & (W / 2)) ? hi : lo;   // uniform cond -> v_cndmask, CSE'd
    }
}

// Padded rank-1 update: r[j] -= lk * L[j][k] for all j in [LO, 64).
template<int J>
__device__ __forceinline__ void upd1(Rows& r, float lk) {
    float ljk = RDLANE(lk, J);                 // literal source lane
    setR<J>(r, fmaf(-lk, ljk, getR<J>(r)));
}
template<int LO, int... Js>
__device__ __forceinline__ void upd_seq(Rows& r, float lk,
                                        std::integer_sequence<int, Js...>) {
    (upd1<LO + Js>(r, lk), ...);
}

// Load row `lane` of the staged matrix into registers (contiguous -> b128s).
template<int... Js>
__device__ __forceinline__ void load_row(Rows& r, const float* Lrow,
                                         std::integer_sequence<int, Js...>) {
    (setR<Js>(r, Lrow[Js]), ...);
}

// One Cholesky phase: k in [KLO, KHI), tree/update width over [ULO, 64).
template<int KLO, int KHI, int ULO>
__device__ __forceinline__ void chol_phase(Rows& r, float* Lsh, int lane) {
#pragma clang loop unroll(disable)
    for (int k = KLO; k < KHI; ++k) {
        float rk  = selR<ULO, 64 - ULO>(r, k); // A[l][k] (valid l >= k)
        float dk  = RDLANE(rk, k);             // A[k][k], uniform
        float inv = RSQ(dk);                   // 1/L[k][k]
        float lk  = rk * inv;                  // L[l][k]
        float st  = (lane == k) ? inv : lk;    // diag slot stores reciprocal
        Lsh[lane * 65 + k] = st;               // sink column k (conflict-free)
        upd_seq<ULO>(r, lk, std::make_integer_sequence<int, 64 - ULO>{});
    }
}

__global__ __launch_bounds__(64, 1)
void gp_precompute(const float* __restrict__ Z, const float* __restrict__ U,
                   const float* __restrict__ sf_p, const float* __restrict__ ell_p,
                   float* __restrict__ ws) {
    __shared__ float Lsh[64 * 65];
    const int lane = threadIdx.x;          // 64 threads = 1 wave
    const float sf  = sf_p[0];
    const float ell = ell_p[0];
    const float inv_ell = 1.0f / ell;
    const float sf2 = sf * sf;

    const float z0 = Z[lane * 3 + 0] * inv_ell;
    const float z1 = Z[lane * 3 + 1] * inv_ell;
    const float z2 = Z[lane * 3 + 2] * inv_ell;

    // Kzz row init, ROLLED (small code): stage row into LDS, reload as b128s.
#pragma clang loop unroll(disable)
    for (int j = 0; j < 64; ++j) {
        float dx = z0 - RDLANE(z0, j);
        float dy = z1 - RDLANE(z1, j);
        float dz = z2 - RDLANE(z2, j);
        float sq = dx * dx + dy * dy + dz * dz;
        Lsh[lane * 65 + j] = sf2 * EXP2F(-0.5f * LOG2E * sq);
    }
    __syncthreads();

    Rows r;
    load_row(r, &Lsh[lane * 65], std::make_integer_sequence<int, 64>{});

    // Right-looking Cholesky, rolled-outer / padded-unrolled-inner.
    chol_phase< 0, 32,  0>(r, Lsh, lane);
    chol_phase<32, 48, 32>(r, Lsh, lane);
    chol_phase<48, 64, 48>(r, Lsh, lane);
    __syncthreads();

    // Solve L^T W = U (column sweep, descending i). Rolled; unroll-8 batches
    // the independent ds_reads ahead of the serial readlane/fma chain.
    float s0 = U[lane * 2 + 0];
    float s1 = U[lane * 2 + 1];
    float w0v = 0.0f, w1v = 0.0f;
#pragma unroll 8
    for (int i = 63; i >= 0; --i) {
        float a   = Lsh[i * 65 + lane];    // L[i][lane]; lane i: 1/L[i][i]
        float rdi = RDLANE(a, i);          // 1/L[i][i]
        float w0  = RDLANE(s0, i) * rdi;   // W[i][0]
        float w1  = RDLANE(s1, i) * rdi;   // W[i][1]
        bool  me  = (lane == i);
        w0v = me ? w0 : w0v;
        w1v = me ? w1 : w1v;
        s0 = fmaf(-a, w0, s0);             // lanes >= i polluted after use
        s1 = fmaf(-a, w1, s1);
    }

    const float dm = -0.5f * LOG2E * (z0 * z0 + z1 * z1 + z2 * z2);
    float4* ws4 = (float4*)ws;
    ws4[lane * 2 + 0] = make_float4(z0, z1, z2, dm);
    ws4[lane * 2 + 1] = make_float4(sf2 * w0v, sf2 * w1v, 0.0f, 0.0f);
}

// ---------------------------------------------------------------------------
// Kernel 2 (byte-identical to R1..R8): out[i,:] = sum_m exp2(c_i+d_m+xt.z)*W[m,:]
// ---------------------------------------------------------------------------
__global__ __launch_bounds__(256) void gp_forward(const float* __restrict__ X,
                                                  const float* __restrict__ ws,
                                                  const float* __restrict__ ell_p,
                                                  float* __restrict__ out, int n) {
    __shared__ float4 P[128];   // 64 structs of {zs0,zs1,zs2,dm | w0,w1,0,0}
    for (int i = threadIdx.x; i < 128; i += 256)
        P[i] = ((const float4*)ws)[i];
    const float inv_ell = 1.0f / ell_p[0];
    __syncthreads();

    const int base = blockIdx.x * (256 * 4) + threadIdx.x;

    float xt0[4], xt1[4], xt2[4], c[4];
#pragma unroll
    for (int p = 0; p < 4; ++p) {
        int i = base + p * 256;
        int ii = (i < n) ? i : 0;            // clamp; result masked on store
        float xs0 = X[ii * 3 + 0] * inv_ell;
        float xs1 = X[ii * 3 + 1] * inv_ell;
        float xs2 = X[ii * 3 + 2] * inv_ell;
        c[p]  = -0.5f * LOG2E * (xs0 * xs0 + xs1 * xs1 + xs2 * xs2);
        xt0[p] = xs0 * LOG2E;
        xt1[p] = xs1 * LOG2E;
        xt2[p] = xs2 * LOG2E;
    }

    float acc0[4] = {0.f, 0.f, 0.f, 0.f};
    float acc1[4] = {0.f, 0.f, 0.f, 0.f};

#pragma unroll 4
    for (int m = 0; m < 64; ++m) {
        const float4 a = P[2 * m + 0];   // zs0, zs1, zs2, dm
        const float4 b = P[2 * m + 1];   // w0, w1, pad, pad
#pragma unroll
        for (int p = 0; p < 4; ++p) {
            float arg = fmaf(xt0[p], a.x,
                        fmaf(xt1[p], a.y,
                        fmaf(xt2[p], a.z, c[p] + a.w)));
            float e = EXP2F(arg);
            acc0[p] = fmaf(e, b.x, acc0[p]);
            acc1[p] = fmaf(e, b.y, acc1[p]);
        }
    }

    float2* out2 = (float2*)out;
#pragma unroll
    for (int p = 0; p < 4; ++p) {
        int i = base + p * 256;
        if (i < n) out2[i] = make_float2(acc0[p], acc1[p]);
    }
}

extern "C" void kernel_launch(void* const* d_in, const int* in_sizes, int n_in,
                              void* d_out, int out_size, void* d_ws, size_t ws_size,
                              hipStream_t stream) {
    // setup_inputs order: t, X, Z, U, sf, ell
    const float* X    = (const float*)d_in[1];
    const float* Z    = (const float*)d_in[2];
    const float* U    = (const float*)d_in[3];
    const float* sf   = (const float*)d_in[4];
    const float* ell  = (const float*)d_in[5];
    float* out = (float*)d_out;
    float* ws  = (float*)d_ws;
    const int N = in_sizes[1] / 3;

    gp_precompute<<<1, 64, 0, stream>>>(Z, U, sf, ell, ws);

    const int PTS_PER_BLOCK = 256 * 4;
    const int blocks = (N + PTS_PER_BLOCK - 1) / PTS_PER_BLOCK;
    gp_forward<<<blocks, 256, 0, stream>>>(X, ws, ell, out, N);
}